// Round 1
// 404.596 us; speedup vs baseline: 1.0717x; 1.0717x over previous
//
#include <hip/hip_runtime.h>

// BinaryLinear: y = x @ sign(W)^T + sign(b)
// R4: pipelined 256x256 i8 GEMM.
//  - ring-4 LDS buffers (128 KiB), staging issued 3 tiles ahead,
//    counted s_waitcnt vmcnt(12) + raw s_barrier (loads never drain) [T4]
//  - XOR chunk swizzle (c ^= (row>>1)&3) on global source + ds_read addr
//    -> conflict-free ds_read_b128 (was ~8-way, 1.7e7 conflicts) [T2]
//  - s_setprio around MFMA cluster [T5]
//  - prep_x + prep_w fused into one kernel (overlapped memory streams)
// Predicted: gemm 206 -> ~125us, MfmaUtil 28 -> ~55%, total 433 -> ~310us.

typedef __attribute__((ext_vector_type(4))) int   i32x4;
typedef __attribute__((ext_vector_type(8))) short short8;
typedef __attribute__((ext_vector_type(4))) float f32x4;

constexpr int M = 8192;
constexpr int N = 4096;
constexpr int K = 4096;

// ---- R4 gemm geometry ----
constexpr int BM = 256, BN = 256, BK = 64;
constexpr int NTILES = K / BK;          // 64
constexpr int TILE_A = BM * BK;         // 16 KiB
constexpr int TILE_B = BN * BK;         // 16 KiB
constexpr int BUFSZ  = TILE_A + TILE_B; // 32 KiB
constexpr int RING   = 4;               // 128 KiB LDS total

// async global -> LDS, 16 B per lane; LDS dest is wave-uniform base + lane*16
__device__ __forceinline__ void load_lds16(const void* g, void* l) {
    __builtin_amdgcn_global_load_lds(
        (const __attribute__((address_space(1))) unsigned int*)g,
        (__attribute__((address_space(3))) unsigned int*)l, 16, 0, 0);
}

// ---------------- fused prep: per-row i8 quant of x  +  W -> sign i8 -------
// blocks [0, M): prep_x row quantization. blocks [M, M+NK/2048): prep_w.
__global__ __launch_bounds__(256) void prep_fused(
    const float* __restrict__ X, const float* __restrict__ W,
    signed char* __restrict__ Xq, signed char* __restrict__ Wq,
    float* __restrict__ Scale) {
    __shared__ float wmax[4];
    const int t = threadIdx.x;

    if (blockIdx.x < M) {
        // ---- prep_x: one block per row, per-row scale = rowmax/127 ----
        const int row = blockIdx.x;
        const float4* xr = reinterpret_cast<const float4*>(X + (size_t)row * K);
        float4 v[4];
        float mx = 0.f;
#pragma unroll
        for (int i = 0; i < 4; ++i) {
            v[i] = xr[t + i * 256];
            mx = fmaxf(mx, fmaxf(fmaxf(fabsf(v[i].x), fabsf(v[i].y)),
                                 fmaxf(fabsf(v[i].z), fabsf(v[i].w))));
        }
#pragma unroll
        for (int off = 32; off > 0; off >>= 1)
            mx = fmaxf(mx, __shfl_down(mx, off));
        if ((t & 63) == 0) wmax[t >> 6] = mx;
        __syncthreads();
        float rmax = fmaxf(fmaxf(wmax[0], wmax[1]), fmaxf(wmax[2], wmax[3]));
        rmax = fmaxf(rmax, 1e-20f);
        const float inv = 127.f / rmax;
        if (t == 0) Scale[row] = rmax * (1.f / 127.f);

        unsigned int* out = reinterpret_cast<unsigned int*>(Xq + (size_t)row * K);
#pragma unroll
        for (int i = 0; i < 4; ++i) {
            int q0 = (int)rintf(v[i].x * inv);
            int q1 = (int)rintf(v[i].y * inv);
            int q2 = (int)rintf(v[i].z * inv);
            int q3 = (int)rintf(v[i].w * inv);
            unsigned int p = (q0 & 255) | ((q1 & 255) << 8) |
                             ((q2 & 255) << 16) | ((unsigned)(q3 & 255) << 24);
            out[t + i * 256] = p;
        }
    } else {
        // ---- prep_w: one thread = 8 elems ----
        size_t i = (size_t)(blockIdx.x - M) * 256 + t;
        const float4* s = reinterpret_cast<const float4*>(W) + i * 2;
        float4 a = s[0], b = s[1];
        auto sg = [](float f) -> unsigned int { return (f >= 0.f) ? 1u : 0xFFu; };
        uint2 o;
        o.x = sg(a.x) | (sg(a.y) << 8) | (sg(a.z) << 16) | (sg(a.w) << 24);
        o.y = sg(b.x) | (sg(b.y) << 8) | (sg(b.z) << 16) | (sg(b.w) << 24);
        reinterpret_cast<uint2*>(Wq)[i] = o;
    }
}

// ---------------- pipelined 256^2 i8 GEMM ----------------
// K-step: issue stage(t+3) -> s_waitcnt vmcnt(12) -> s_barrier -> ds_read
// frags (swizzled) -> setprio(1) -> 32 MFMA -> setprio(0) -> s_barrier.
template <int VMN>
__device__ __forceinline__ void kstep(const signed char* smem, int t,
                                      int wm, int wn, int rl, int cq16,
                                      i32x4 (&acc)[8][4]) {
    asm volatile("s_waitcnt vmcnt(%0)" :: "i"(VMN) : "memory");
    __builtin_amdgcn_s_barrier();
    asm volatile("" ::: "memory");  // keep ds_reads below the barrier

    const signed char* Ab = smem + (t & (RING - 1)) * BUFSZ;
    const signed char* Bb = Ab + TILE_A;
    i32x4 a[8], b[4];
#pragma unroll
    for (int mi = 0; mi < 8; ++mi)
        a[mi] = *reinterpret_cast<const i32x4*>(
            Ab + (wm * 128 + mi * 16 + rl) * BK + cq16);
#pragma unroll
    for (int ni = 0; ni < 4; ++ni)
        b[ni] = *reinterpret_cast<const i32x4*>(
            Bb + (wn * 64 + ni * 16 + rl) * BK + cq16);

    __builtin_amdgcn_s_setprio(1);
#pragma unroll
    for (int mi = 0; mi < 8; ++mi)
#pragma unroll
        for (int ni = 0; ni < 4; ++ni)
            acc[mi][ni] = __builtin_amdgcn_mfma_i32_16x16x64_i8(
                a[mi], b[ni], acc[mi][ni], 0, 0, 0);
    __builtin_amdgcn_s_setprio(0);

    asm volatile("" ::: "memory");  // keep ds_reads above the end barrier
    __builtin_amdgcn_s_barrier();
}

__global__ __launch_bounds__(512, 2) void gemm_i8_p(
    const signed char* __restrict__ Aq, const signed char* __restrict__ Bq,
    const float* __restrict__ Scale, const float* __restrict__ Bias,
    float* __restrict__ OUT) {
    __shared__ signed char smem[RING * BUFSZ];  // 128 KiB

    const int tid  = threadIdx.x;
    const int lane = tid & 63;
    const int w    = tid >> 6;   // 0..7
    const int wm   = w >> 2;     // 0..1 (128-row strip)
    const int wn   = w & 3;      // 0..3 (64-col strip)
    const int rl   = lane & 15;
    // swizzled 16B-chunk offset for fragment reads: c' = (lane>>4) ^ ((rl>>1)&3)
    const int cq16 = (((lane >> 4) ^ ((rl >> 1) & 3)) << 4);

    // XCD-aware block swizzle (512 blocks, 512 % 8 == 0 -> simple bijection)
    const int wg  = blockIdx.x;
    const int lin = (wg & 7) * 64 + (wg >> 3);
    const int n0  = (lin & 15) * BN;
    const int m0  = (lin >> 4) * BM;

    // staging source: linear LDS dest (row = tid/4 [+128], chunk = tid&3),
    // global chunk = linear chunk ^ swizzle(row)  (same involution as reads)
    const int srow = tid >> 2;                       // 0..127
    const int cg   = ((tid & 3) ^ ((srow >> 1) & 3)) * 16;
    const signed char* gA0 = Aq + (size_t)(m0 + srow)       * K + cg;
    const signed char* gA1 = Aq + (size_t)(m0 + 128 + srow) * K + cg;
    const signed char* gB0 = Bq + (size_t)(n0 + srow)       * K + cg;
    const signed char* gB1 = Bq + (size_t)(n0 + 128 + srow) * K + cg;
    signed char* lbase = smem + w * 1024;            // wave-uniform

    auto stage = [&](int t) {
        signed char* d = lbase + (t & (RING - 1)) * BUFSZ;
        const size_t ko = (size_t)t * BK;
        load_lds16(gA0 + ko, d);
        load_lds16(gA1 + ko, d + 8192);
        load_lds16(gB0 + ko, d + TILE_A);
        load_lds16(gB1 + ko, d + TILE_A + 8192);
    };

    i32x4 acc[8][4];
#pragma unroll
    for (int mi = 0; mi < 8; ++mi)
#pragma unroll
        for (int ni = 0; ni < 4; ++ni)
            acc[mi][ni] = (i32x4){0, 0, 0, 0};

    // prologue: 3 tiles in flight
    stage(0); stage(1); stage(2);

    int t = 0;
    for (; t < NTILES - 3; ++t) {
        stage(t + 3);                       // 4 loads -> <=16 outstanding
        kstep<12>(smem, t, wm, wn, rl, cq16, acc);  // retire tile t's 4
    }
    kstep<8>(smem, t, wm, wn, rl, cq16, acc); ++t;  // tail: drain 4 per step
    kstep<4>(smem, t, wm, wn, rl, cq16, acc); ++t;
    kstep<0>(smem, t, wm, wn, rl, cq16, acc);

    // epilogue: C/D layout col=lane&15, row=(lane>>4)*4+reg
#pragma unroll
    for (int ni = 0; ni < 4; ++ni) {
        const int gcol = n0 + wn * 64 + ni * 16 + rl;
        const float sb = (Bias[gcol] >= 0.f) ? 1.f : -1.f;
#pragma unroll
        for (int mi = 0; mi < 8; ++mi) {
            const int growb = m0 + wm * 128 + mi * 16 + (lane >> 4) * 4;
            const float4 sc = *reinterpret_cast<const float4*>(&Scale[growb]);
            OUT[(size_t)(growb + 0) * N + gcol] = (float)acc[mi][ni][0] * sc.x + sb;
            OUT[(size_t)(growb + 1) * N + gcol] = (float)acc[mi][ni][1] * sc.y + sb;
            OUT[(size_t)(growb + 2) * N + gcol] = (float)acc[mi][ni][2] * sc.z + sb;
            OUT[(size_t)(growb + 3) * N + gcol] = (float)acc[mi][ni][3] * sc.w + sb;
        }
    }
}

// ---------------- fallback (R1 kernel): used only if ws_size is too small ----
constexpr int MT   = 128;
constexpr int NTF  = 128;
constexpr int LDSS = 40;
constexpr int KTB  = 32;
__device__ __forceinline__ unsigned short f2b(float f) {
    unsigned int u = __builtin_bit_cast(unsigned int, f);
    u += 0x7FFFu + ((u >> 16) & 1u);
    return (unsigned short)(u >> 16);
}
__global__ __launch_bounds__(256) void binlin_fallback(
    const float* __restrict__ X, const float* __restrict__ W,
    const float* __restrict__ B, float* __restrict__ OUT) {
    __shared__ unsigned short As[MT][LDSS];
    __shared__ unsigned short Bs[NTF][LDSS];
    const int tid  = threadIdx.x;
    const int lane = tid & 63;
    const int wave = tid >> 6;
    const int wm   = wave >> 1;
    const int wn   = wave & 1;
    const int m0 = blockIdx.y * MT;
    const int n0 = blockIdx.x * NTF;
    const int rl = lane & 15;
    const int kq = (lane >> 4) * 8;
    f32x4 acc[4][4];
#pragma unroll
    for (int mi = 0; mi < 4; ++mi)
#pragma unroll
        for (int ni = 0; ni < 4; ++ni)
            acc[mi][ni] = (f32x4){0.f, 0.f, 0.f, 0.f};
    for (int k0 = 0; k0 < K; k0 += KTB) {
#pragma unroll
        for (int it = 0; it < 4; ++it) {
            int g = tid + it * 256, row = g >> 3, c4 = (g & 7) << 2;
            float4 v = *reinterpret_cast<const float4*>(&X[(size_t)(m0 + row) * K + k0 + c4]);
            ushort4 h;
            h.x = f2b(v.x); h.y = f2b(v.y); h.z = f2b(v.z); h.w = f2b(v.w);
            *reinterpret_cast<ushort4*>(&As[row][c4]) = h;
        }
#pragma unroll
        for (int it = 0; it < 4; ++it) {
            int g = tid + it * 256, row = g >> 3, c4 = (g & 7) << 2;
            float4 v = *reinterpret_cast<const float4*>(&W[(size_t)(n0 + row) * K + k0 + c4]);
            ushort4 h;
            h.x = (v.x >= 0.f) ? 0x3F80u : 0xBF80u;
            h.y = (v.y >= 0.f) ? 0x3F80u : 0xBF80u;
            h.z = (v.z >= 0.f) ? 0x3F80u : 0xBF80u;
            h.w = (v.w >= 0.f) ? 0x3F80u : 0xBF80u;
            *reinterpret_cast<ushort4*>(&Bs[row][c4]) = h;
        }
        __syncthreads();
        short8 a[4], b[4];
#pragma unroll
        for (int mi = 0; mi < 4; ++mi)
            a[mi] = *reinterpret_cast<const short8*>(&As[wm * 64 + mi * 16 + rl][kq]);
#pragma unroll
        for (int ni = 0; ni < 4; ++ni)
            b[ni] = *reinterpret_cast<const short8*>(&Bs[wn * 64 + ni * 16 + rl][kq]);
#pragma unroll
        for (int mi = 0; mi < 4; ++mi)
#pragma unroll
            for (int ni = 0; ni < 4; ++ni)
                acc[mi][ni] = __builtin_amdgcn_mfma_f32_16x16x32_bf16(
                    a[mi], b[ni], acc[mi][ni], 0, 0, 0);
        __syncthreads();
    }
#pragma unroll
    for (int ni = 0; ni < 4; ++ni) {
        int gcol = n0 + wn * 64 + ni * 16 + rl;
        float sb = (B[gcol] >= 0.f) ? 1.f : -1.f;
#pragma unroll
        for (int mi = 0; mi < 4; ++mi) {
            int growb = m0 + wm * 64 + mi * 16 + (lane >> 4) * 4;
#pragma unroll
            for (int r = 0; r < 4; ++r)
                OUT[(size_t)(growb + r) * N + gcol] = acc[mi][ni][r] + sb;
        }
    }
}

extern "C" void kernel_launch(void* const* d_in, const int* in_sizes, int n_in,
                              void* d_out, int out_size, void* d_ws, size_t ws_size,
                              hipStream_t stream) {
    const float* x  = (const float*)d_in[0];
    const float* w  = (const float*)d_in[1];
    const float* b  = (const float*)d_in[2];
    float* out      = (float*)d_out;

    // ws layout: Xq [M*K i8] | Wq [N*K i8] | Scale [M f32]
    const size_t need = (size_t)M * K + (size_t)N * K + (size_t)M * sizeof(float);
    if (ws_size >= need) {
        signed char* Xq = (signed char*)d_ws;
        signed char* Wq = Xq + (size_t)M * K;
        float* Scale    = (float*)(Wq + (size_t)N * K);

        const unsigned prepw_blocks = (unsigned)((size_t)N * K / 8 / 256);  // 8192
        prep_fused<<<dim3(M + prepw_blocks), dim3(256), 0, stream>>>(x, w, Xq, Wq, Scale);

        gemm_i8_p<<<dim3((M / BM) * (N / BN)), dim3(512), 0, stream>>>(
            Xq, Wq, Scale, b, out);
    } else {
        dim3 grid(N / NTF, M / MT);
        binlin_fallback<<<grid, dim3(256), 0, stream>>>(x, w, b, out);
    }
}

// Round 2
// 403.186 us; speedup vs baseline: 1.0754x; 1.0035x over previous
//
#include <hip/hip_runtime.h>

// BinaryLinear: y = x @ sign(W)^T + sign(b)
// R5: 8-phase-schedule i8 GEMM (m201 port) + wave-independent prep.
//  - per K-step: 4 phases {ds_read subtile | 1 global_load_lds | barrier |
//    lgkmcnt(0) | setprio(1) 8xMFMA setprio(0) | barrier} -> LDS-port drain
//    overlaps MFMA across waves (was serialized: 1152cy LDS + 1306cy MFMA/step)
//  - counted vmcnt once per K-step (8 steady / 4 / 0 tail), ring-4 buffers
//  - T2 XOR chunk swizzle kept (conflicts were 0)
//  - prep: 1 wave per x-row (no LDS/syncthreads), grid-stride sign(W)
// Predicted: gemm 161 -> ~115us, MfmaUtil 35 -> ~55%, total 404 -> ~300us.

typedef __attribute__((ext_vector_type(4))) int   i32x4;
typedef __attribute__((ext_vector_type(8))) short short8;
typedef __attribute__((ext_vector_type(4))) float f32x4;

constexpr int M = 8192;
constexpr int N = 4096;
constexpr int K = 4096;

// ---- gemm geometry ----
constexpr int BM = 256, BN = 256, BK = 64;
constexpr int NTILES = K / BK;          // 64
constexpr int TILE_A = BM * BK;         // 16 KiB
constexpr int TILE_B = BN * BK;         // 16 KiB
constexpr int BUFSZ  = TILE_A + TILE_B; // 32 KiB
constexpr int RING   = 4;               // 128 KiB LDS total

__device__ __forceinline__ void load_lds16(const void* g, void* l) {
    __builtin_amdgcn_global_load_lds(
        (const __attribute__((address_space(1))) unsigned int*)g,
        (__attribute__((address_space(3))) unsigned int*)l, 16, 0, 0);
}

// ---------------- fused prep ----------------
// blocks [0, XB): prep_x, one WAVE per row (4 rows/block), no LDS, no sync.
// blocks [XB, XB+WB): prep_w grid-stride, 8 chunks of 32B per thread.
constexpr int XB = M / 4;          // 2048
constexpr int WB = 1024;
constexpr int WCH = N * K / 8;     // uint2 chunks (8 i8 each) = 2M

__global__ __launch_bounds__(256) void prep_fused(
    const float* __restrict__ X, const float* __restrict__ W,
    signed char* __restrict__ Xq, signed char* __restrict__ Wq,
    float* __restrict__ Scale) {
    const int t    = threadIdx.x;
    const int lane = t & 63;
    const int wv   = t >> 6;

    if (blockIdx.x < XB) {
        // ---- prep_x: wave wv handles row 4*blk + wv ----
        const int row = blockIdx.x * 4 + wv;
        const float4* xr = reinterpret_cast<const float4*>(X + (size_t)row * K);
        float4 v[16];
        float mx = 0.f;
#pragma unroll
        for (int i = 0; i < 4; ++i) {
#pragma unroll
            for (int j = 0; j < 4; ++j) {
                float4 f = xr[4 * lane + 256 * i + j];
                v[4 * i + j] = f;
                mx = fmaxf(mx, fmaxf(fmaxf(fabsf(f.x), fabsf(f.y)),
                                     fmaxf(fabsf(f.z), fabsf(f.w))));
            }
        }
#pragma unroll
        for (int off = 32; off > 0; off >>= 1)
            mx = fmaxf(mx, __shfl_down(mx, off));
        mx = __shfl(mx, 0);                    // broadcast wave max
        const float rmax = fmaxf(mx, 1e-20f);
        const float inv  = 127.f / rmax;
        if (lane == 0) Scale[row] = rmax * (1.f / 127.f);

        uint4* out4 = reinterpret_cast<uint4*>(Xq + (size_t)row * K);
#pragma unroll
        for (int i = 0; i < 4; ++i) {
            uint4 o;
            unsigned int* op = &o.x;
#pragma unroll
            for (int j = 0; j < 4; ++j) {
                float4 f = v[4 * i + j];
                int q0 = (int)rintf(f.x * inv);
                int q1 = (int)rintf(f.y * inv);
                int q2 = (int)rintf(f.z * inv);
                int q3 = (int)rintf(f.w * inv);
                op[j] = (q0 & 255) | ((q1 & 255) << 8) |
                        ((q2 & 255) << 16) | ((unsigned)(q3 & 255) << 24);
            }
            out4[lane + 64 * i] = o;
        }
    } else {
        // ---- prep_w: grid-stride, 8 chunks/thread ----
        const float4* W4 = reinterpret_cast<const float4*>(W);
        uint2* O = reinterpret_cast<uint2*>(Wq);
        auto sg = [](float f) -> unsigned int { return (f >= 0.f) ? 1u : 0xFFu; };
        size_t idx = (size_t)(blockIdx.x - XB) * 256 + t;
        const size_t stride = (size_t)WB * 256;
        for (size_t c = idx; c < (size_t)WCH; c += stride) {
            float4 a = W4[c * 2], b = W4[c * 2 + 1];
            uint2 o;
            o.x = sg(a.x) | (sg(a.y) << 8) | (sg(a.z) << 16) | (sg(a.w) << 24);
            o.y = sg(b.x) | (sg(b.y) << 8) | (sg(b.z) << 16) | (sg(b.w) << 24);
            O[c] = o;
        }
    }
}

// ---------------- 8-phase pipelined 256^2 i8 GEMM ----------------
struct GemmCtx {
    const signed char* gA0;
    const signed char* gA1;
    const signed char* gB0;
    const signed char* gB1;
    signed char* lbase;     // wave-uniform stage dest base
    int wm, wn, rl, cq16;
};

// Phase P of K-step t. Reads its A sub-pair (P==0 also reads all B), issues
// stage load #P for tile t+3 (if STAGE), barrier, lgkm(0), 8 MFMA.
// P<3: trailing barrier here. P==3: caller does vmcnt + trailing barrier.
template <int P, bool STAGE>
__device__ __forceinline__ void phase(
    const GemmCtx& c, const signed char* Ab, const signed char* Bb,
    signed char* dst, size_t ko,
    i32x4 (&a)[2], i32x4 (&b)[4], i32x4 (&acc)[8][4]) {
    if constexpr (P == 0) {
#pragma unroll
        for (int ni = 0; ni < 4; ++ni)
            b[ni] = *reinterpret_cast<const i32x4*>(
                Bb + (c.wn * 64 + ni * 16 + c.rl) * BK + c.cq16);
    }
    a[0] = *reinterpret_cast<const i32x4*>(
        Ab + (c.wm * 128 + (2 * P + 0) * 16 + c.rl) * BK + c.cq16);
    a[1] = *reinterpret_cast<const i32x4*>(
        Ab + (c.wm * 128 + (2 * P + 1) * 16 + c.rl) * BK + c.cq16);
    if constexpr (STAGE) {
        if constexpr (P == 0) load_lds16(c.gA0 + ko, dst);
        if constexpr (P == 1) load_lds16(c.gA1 + ko, dst + 8192);
        if constexpr (P == 2) load_lds16(c.gB0 + ko, dst + TILE_A);
        if constexpr (P == 3) load_lds16(c.gB1 + ko, dst + TILE_A + 8192);
    }
    asm volatile("" ::: "memory");
    __builtin_amdgcn_s_barrier();
    asm volatile("s_waitcnt lgkmcnt(0)" ::: "memory");
    __builtin_amdgcn_sched_barrier(0);
    __builtin_amdgcn_s_setprio(1);
#pragma unroll
    for (int j = 0; j < 2; ++j)
#pragma unroll
        for (int ni = 0; ni < 4; ++ni)
            acc[2 * P + j][ni] = __builtin_amdgcn_mfma_i32_16x16x64_i8(
                a[j], b[ni], acc[2 * P + j][ni], 0, 0, 0);
    __builtin_amdgcn_s_setprio(0);
    asm volatile("" ::: "memory");
    if constexpr (P < 3) __builtin_amdgcn_s_barrier();
}

// One K-step: 4 phases; VMEND = counted vmcnt before the step-end barrier
// (wait for tile t+1's loads to have landed). VMEND < 0: no wait/barrier
// (last step).
template <bool STAGE, int VMEND>
__device__ __forceinline__ void kstep8(
    const GemmCtx& c, const signed char* smem, int t,
    i32x4 (&a)[2], i32x4 (&b)[4], i32x4 (&acc)[8][4]) {
    const signed char* Ab = smem + (t & (RING - 1)) * BUFSZ;
    const signed char* Bb = Ab + TILE_A;
    signed char* dst = c.lbase + ((t + 3) & (RING - 1)) * BUFSZ;
    const size_t ko = (size_t)(t + 3) * BK;

    phase<0, STAGE>(c, Ab, Bb, dst, ko, a, b, acc);
    phase<1, STAGE>(c, Ab, Bb, dst, ko, a, b, acc);
    phase<2, STAGE>(c, Ab, Bb, dst, ko, a, b, acc);
    phase<3, STAGE>(c, Ab, Bb, dst, ko, a, b, acc);
    if constexpr (VMEND >= 0) {
        asm volatile("s_waitcnt vmcnt(%0)" :: "i"(VMEND) : "memory");
        __builtin_amdgcn_s_barrier();
        asm volatile("" ::: "memory");
    }
}

__global__ __launch_bounds__(512, 2) void gemm_i8_p(
    const signed char* __restrict__ Aq, const signed char* __restrict__ Bq,
    const float* __restrict__ Scale, const float* __restrict__ Bias,
    float* __restrict__ OUT) {
    __shared__ signed char smem[RING * BUFSZ];  // 128 KiB

    const int tid  = threadIdx.x;
    const int lane = tid & 63;
    const int w    = tid >> 6;   // 0..7
    GemmCtx c;
    c.wm = w >> 2;               // 0..1 (128-row strip)
    c.wn = w & 3;                // 0..3 (64-col strip)
    c.rl = lane & 15;
    // T2 swizzle: chunk' = (lane>>4) ^ ((rl>>1)&3)
    c.cq16 = (((lane >> 4) ^ ((c.rl >> 1) & 3)) << 4);

    // XCD-aware block swizzle (512 blocks, 512 % 8 == 0 -> bijective)
    const int wg  = blockIdx.x;
    const int lin = (wg & 7) * 64 + (wg >> 3);
    const int n0  = (lin & 15) * BN;
    const int m0  = (lin >> 4) * BM;

    // staging: linear LDS dest (row = tid/4 [+128], chunk = tid&3),
    // global chunk = linear chunk ^ swizzle(row) (same involution as reads)
    const int srow = tid >> 2;                       // 0..127
    const int cg   = ((tid & 3) ^ ((srow >> 1) & 3)) * 16;
    c.gA0 = Aq + (size_t)(m0 + srow)       * K + cg;
    c.gA1 = Aq + (size_t)(m0 + 128 + srow) * K + cg;
    c.gB0 = Bq + (size_t)(n0 + srow)       * K + cg;
    c.gB1 = Bq + (size_t)(n0 + 128 + srow) * K + cg;
    c.lbase = smem + w * 1024;                       // wave-uniform

    auto stage_full = [&](int t) {
        signed char* d = c.lbase + (t & (RING - 1)) * BUFSZ;
        const size_t ko = (size_t)t * BK;
        load_lds16(c.gA0 + ko, d);
        load_lds16(c.gA1 + ko, d + 8192);
        load_lds16(c.gB0 + ko, d + TILE_A);
        load_lds16(c.gB1 + ko, d + TILE_A + 8192);
    };

    i32x4 acc[8][4];
#pragma unroll
    for (int mi = 0; mi < 8; ++mi)
#pragma unroll
        for (int ni = 0; ni < 4; ++ni)
            acc[mi][ni] = (i32x4){0, 0, 0, 0};
    i32x4 a[2], b[4];

    // prologue: 3 tiles in flight; tile-0 handshake
    stage_full(0); stage_full(1); stage_full(2);
    asm volatile("s_waitcnt vmcnt(8)" ::: "memory");
    __builtin_amdgcn_s_barrier();
    asm volatile("" ::: "memory");

    int t = 0;
    for (; t < NTILES - 3; ++t)            // t = 0..60: stage t+3, wait t+1
        kstep8<true, 8>(c, smem, t, a, b, acc);
    kstep8<false, 4>(c, smem, t, a, b, acc); ++t;   // t=61
    kstep8<false, 0>(c, smem, t, a, b, acc); ++t;   // t=62
    kstep8<false, -1>(c, smem, t, a, b, acc);       // t=63 (no end wait)

    // epilogue: C/D layout col=lane&15, row=(lane>>4)*4+reg
#pragma unroll
    for (int ni = 0; ni < 4; ++ni) {
        const int gcol = n0 + c.wn * 64 + ni * 16 + c.rl;
        const float sb = (Bias[gcol] >= 0.f) ? 1.f : -1.f;
#pragma unroll
        for (int mi = 0; mi < 8; ++mi) {
            const int growb = m0 + c.wm * 128 + mi * 16 + (lane >> 4) * 4;
            const float4 sc = *reinterpret_cast<const float4*>(&Scale[growb]);
            OUT[(size_t)(growb + 0) * N + gcol] = (float)acc[mi][ni][0] * sc.x + sb;
            OUT[(size_t)(growb + 1) * N + gcol] = (float)acc[mi][ni][1] * sc.y + sb;
            OUT[(size_t)(growb + 2) * N + gcol] = (float)acc[mi][ni][2] * sc.z + sb;
            OUT[(size_t)(growb + 3) * N + gcol] = (float)acc[mi][ni][3] * sc.w + sb;
        }
    }
}

// ---------------- fallback (R1 kernel): used only if ws_size is too small ----
constexpr int MT   = 128;
constexpr int NTF  = 128;
constexpr int LDSS = 40;
constexpr int KTB  = 32;
__device__ __forceinline__ unsigned short f2b(float f) {
    unsigned int u = __builtin_bit_cast(unsigned int, f);
    u += 0x7FFFu + ((u >> 16) & 1u);
    return (unsigned short)(u >> 16);
}
__global__ __launch_bounds__(256) void binlin_fallback(
    const float* __restrict__ X, const float* __restrict__ W,
    const float* __restrict__ B, float* __restrict__ OUT) {
    __shared__ unsigned short As[MT][LDSS];
    __shared__ unsigned short Bs[NTF][LDSS];
    const int tid  = threadIdx.x;
    const int lane = tid & 63;
    const int wave = tid >> 6;
    const int wm   = wave >> 1;
    const int wn   = wave & 1;
    const int m0 = blockIdx.y * MT;
    const int n0 = blockIdx.x * NTF;
    const int rl = lane & 15;
    const int kq = (lane >> 4) * 8;
    f32x4 acc[4][4];
#pragma unroll
    for (int mi = 0; mi < 4; ++mi)
#pragma unroll
        for (int ni = 0; ni < 4; ++ni)
            acc[mi][ni] = (f32x4){0.f, 0.f, 0.f, 0.f};
    for (int k0 = 0; k0 < K; k0 += KTB) {
#pragma unroll
        for (int it = 0; it < 4; ++it) {
            int g = tid + it * 256, row = g >> 3, c4 = (g & 7) << 2;
            float4 v = *reinterpret_cast<const float4*>(&X[(size_t)(m0 + row) * K + k0 + c4]);
            ushort4 h;
            h.x = f2b(v.x); h.y = f2b(v.y); h.z = f2b(v.z); h.w = f2b(v.w);
            *reinterpret_cast<ushort4*>(&As[row][c4]) = h;
        }
#pragma unroll
        for (int it = 0; it < 4; ++it) {
            int g = tid + it * 256, row = g >> 3, c4 = (g & 7) << 2;
            float4 v = *reinterpret_cast<const float4*>(&W[(size_t)(n0 + row) * K + k0 + c4]);
            ushort4 h;
            h.x = (v.x >= 0.f) ? 0x3F80u : 0xBF80u;
            h.y = (v.y >= 0.f) ? 0x3F80u : 0xBF80u;
            h.z = (v.z >= 0.f) ? 0x3F80u : 0xBF80u;
            h.w = (v.w >= 0.f) ? 0x3F80u : 0xBF80u;
            *reinterpret_cast<ushort4*>(&Bs[row][c4]) = h;
        }
        __syncthreads();
        short8 a[4], b[4];
#pragma unroll
        for (int mi = 0; mi < 4; ++mi)
            a[mi] = *reinterpret_cast<const short8*>(&As[wm * 64 + mi * 16 + rl][kq]);
#pragma unroll
        for (int ni = 0; ni < 4; ++ni)
            b[ni] = *reinterpret_cast<const short8*>(&Bs[wn * 64 + ni * 16 + rl][kq]);
#pragma unroll
        for (int mi = 0; mi < 4; ++mi)
#pragma unroll
            for (int ni = 0; ni < 4; ++ni)
                acc[mi][ni] = __builtin_amdgcn_mfma_f32_16x16x32_bf16(
                    a[mi], b[ni], acc[mi][ni], 0, 0, 0);
        __syncthreads();
    }
#pragma unroll
    for (int ni = 0; ni < 4; ++ni) {
        int gcol = n0 + wn * 64 + ni * 16 + rl;
        float sb = (B[gcol] >= 0.f) ? 1.f : -1.f;
#pragma unroll
        for (int mi = 0; mi < 4; ++mi) {
            int growb = m0 + wm * 64 + mi * 16 + (lane >> 4) * 4;
#pragma unroll
            for (int r = 0; r < 4; ++r)
                OUT[(size_t)(growb + r) * N + gcol] = acc[mi][ni][r] + sb;
        }
    }
}

extern "C" void kernel_launch(void* const* d_in, const int* in_sizes, int n_in,
                              void* d_out, int out_size, void* d_ws, size_t ws_size,
                              hipStream_t stream) {
    const float* x  = (const float*)d_in[0];
    const float* w  = (const float*)d_in[1];
    const float* b  = (const float*)d_in[2];
    float* out      = (float*)d_out;

    // ws layout: Xq [M*K i8] | Wq [N*K i8] | Scale [M f32]
    const size_t need = (size_t)M * K + (size_t)N * K + (size_t)M * sizeof(float);
    if (ws_size >= need) {
        signed char* Xq = (signed char*)d_ws;
        signed char* Wq = Xq + (size_t)M * K;
        float* Scale    = (float*)(Wq + (size_t)N * K);

        prep_fused<<<dim3(XB + WB), dim3(256), 0, stream>>>(x, w, Xq, Wq, Scale);
        gemm_i8_p<<<dim3((M / BM) * (N / BN)), dim3(512), 0, stream>>>(
            Xq, Wq, Scale, b, out);
    } else {
        dim3 grid(N / NTF, M / MT);
        binlin_fallback<<<grid, dim3(256), 0, stream>>>(x, w, b, out);
    }
}